// Round 7
// baseline (95.731 us; speedup 1.0000x reference)
//
#include <hip/hip_runtime.h>

// DWA_CNN: B=32, T=2048, C=128, K=3, F=8, P=2046
// v6-DIAG: v5b wrapped in 8x repeat to surface the kernel in rocprof top-5
// (it was hidden under ~40us harness fills). Output identical each rep ->
// still correct/deterministic. Marginal rep cost m=(dur8-dur1)/7 decomposes
// fixed vs steady-state cost; counters (VALUBusy/MfmaUtil/FETCH/WRITE/occ)
// identify the real bottleneck. This round is instrumentation, not perf.

#define TT   30
#define RWS  32
#define GSTR 27
#define BIGV 1234567891011.0f
#define REPS 8

typedef __attribute__((ext_vector_type(8))) short short8v;
typedef __attribute__((ext_vector_type(4))) float f32x4;

static __device__ inline unsigned pk2(float lo, float hi) {
  unsigned r;
  asm("v_cvt_pk_bf16_f32 %0, %1, %2" : "=v"(r) : "v"(lo), "v"(hi));
  return r;
}
static __device__ inline float bf2f(unsigned short h) {
  return __uint_as_float(((unsigned)h) << 16);
}
static __device__ inline int swzi(int row, int c) {
  return row * 128 + (((c >> 3) ^ (row & 7)) << 3) + (c & 7);
}

__global__ __launch_bounds__(128, 4) void dwa_cnn_kernel(
    const float* __restrict__ x, const float* __restrict__ w,
    const float* __restrict__ bias, float* __restrict__ out)
{
  constexpr int T = 2048, C = 128, P = 2046;

  __shared__ alignas(16) unsigned short Xs[RWS * 128];
  __shared__ alignas(16) unsigned short Wb[RWS * 128];
  __shared__ float WN[24];
  __shared__ float BI[8];
  float* G = reinterpret_cast<float*>(Xs);

  const int tid  = threadIdx.x;
  const int b    = blockIdx.y;
  const int p0   = blockIdx.x * TT;
  const int wave = tid >> 6;
  const int lane = tid & 63;

  const float breg = (tid < 8) ? bias[tid] : 0.f;

  const int srow = tid >> 2, c0 = (tid & 3) * 32;
  const int grow = (p0 + srow < T) ? (p0 + srow) : (T - 1);
  const float* xr = &x[((size_t)b * T + grow) * C + c0];

  #pragma unroll 1
  for (int rep = 0; rep < REPS; ++rep) {
    asm volatile("" ::: "memory");   // force per-rep re-load of x/w

    // ---- x load: 8x dwordx4 ----
    float4 xv[8];
    #pragma unroll
    for (int m = 0; m < 8; ++m) xv[m] = *(const float4*)(xr + m * 4);

    // ---- w -> Wb ----
    #pragma unroll
    for (int j = 0; j < 6; ++j) {
      const int i4 = j * 512 + tid * 4;
      const float4 wv = *(const float4*)&w[i4];
      const int k = i4 >> 10, c = (i4 >> 3) & 127, f0 = i4 & 7;
      const int q = k * 8 + f0;
      Wb[swzi(q + 0, c)] = (unsigned short)pk2(wv.x, wv.x);
      Wb[swzi(q + 1, c)] = (unsigned short)pk2(wv.y, wv.y);
      Wb[swzi(q + 2, c)] = (unsigned short)pk2(wv.z, wv.z);
      Wb[swzi(q + 3, c)] = (unsigned short)pk2(wv.w, wv.w);
    }
    { uint4 z = {0, 0, 0, 0}; *(uint4*)&Wb[3072 + tid * 8] = z; }

    // ---- norm partial + pack x -> Xs ----
    float xn = 0.f;
    #pragma unroll
    for (int m = 0; m < 8; ++m)
      xn = fmaf(xv[m].x, xv[m].x, fmaf(xv[m].y, xv[m].y,
           fmaf(xv[m].z, xv[m].z, fmaf(xv[m].w, xv[m].w, xn))));
    #pragma unroll
    for (int m = 0; m < 4; ++m) {
      uint4 pkv;
      pkv.x = pk2(xv[2*m].x,   xv[2*m].y);
      pkv.y = pk2(xv[2*m].z,   xv[2*m].w);
      pkv.z = pk2(xv[2*m+1].x, xv[2*m+1].y);
      pkv.w = pk2(xv[2*m+1].z, xv[2*m+1].w);
      *(uint4*)&Xs[swzi(srow, c0 + m * 8)] = pkv;
    }
    xn += __shfl_xor(xn, 1);
    xn += __shfl_xor(xn, 2);

    __syncthreads();

    // ---- fragments + MFMA ----
    const int g = lane >> 4;
    const int arow = wave * 16 + (lane & 15);
    const int q0 = lane & 15;
    short8v af[4], b0f[4], b1f[4];
    #pragma unroll
    for (int kk = 0; kk < 4; ++kk) {
      const int oct = kk * 4 + g;
      af[kk]  = *(const short8v*)&Xs[swzi(arow,    oct * 8)];
      b0f[kk] = *(const short8v*)&Wb[swzi(q0,      oct * 8)];
      b1f[kk] = *(const short8v*)&Wb[swzi(q0 + 16, oct * 8)];
    }

    f32x4 acc0 = {0.f, 0.f, 0.f, 0.f}, acc1 = {0.f, 0.f, 0.f, 0.f};
    #pragma unroll
    for (int kk = 0; kk < 4; ++kk) {
      acc0 = __builtin_amdgcn_mfma_f32_16x16x32_bf16(af[kk], b0f[kk], acc0, 0, 0, 0);
      acc1 = __builtin_amdgcn_mfma_f32_16x16x32_bf16(af[kk], b1f[kk], acc1, 0, 0, 0);
    }

    float wn0 = 0.f, wn1 = 0.f;
    if (wave == 0) {
      #pragma unroll
      for (int kk = 0; kk < 4; ++kk) {
        #pragma unroll
        for (int e = 0; e < 8; ++e) {
          const float v0 = bf2f((unsigned short)b0f[kk][e]);
          wn0 = fmaf(v0, v0, wn0);
          const float v1 = bf2f((unsigned short)b1f[kk][e]);
          wn1 = fmaf(v1, v1, wn1);
        }
      }
      wn0 += __shfl_xor(wn0, 16); wn0 += __shfl_xor(wn0, 32);
      wn1 += __shfl_xor(wn1, 16); wn1 += __shfl_xor(wn1, 32);
    }

    __syncthreads();  // Xs reads done -> reuse as G

    {
      const int col = lane & 15, rq = (lane >> 4) * 4;
      #pragma unroll
      for (int r = 0; r < 4; ++r)
        G[(wave * 16 + rq + r) * GSTR + col] = acc0[r];
      if (col < 8) {
        #pragma unroll
        for (int r = 0; r < 4; ++r)
          G[(wave * 16 + rq + r) * GSTR + 16 + col] = acc1[r];
      }
    }
    if ((tid & 3) == 0) G[srow * GSTR + 24] = xn;
    if (wave == 0 && lane < 16) WN[lane] = wn0;
    if (wave == 0 && lane < 8)  WN[16 + lane] = wn1;
    if (tid < 8) BI[tid] = breg;

    __syncthreads();

    // ---- phase 2 ----
    #pragma unroll
    for (int it = 0; it < 2; ++it) {
      const int o = tid + it * 128;
      if (o < TT * 8) {
        const int pl = o >> 3, f = o & 7;
        const int p  = p0 + pl;

        float xnv[3], dots[3][3], D[3][3];
        #pragma unroll
        for (int i = 0; i < 3; ++i) {
          xnv[i] = G[(pl + i) * GSTR + 24];
          #pragma unroll
          for (int j = 0; j < 3; ++j) dots[i][j] = G[(pl + i) * GSTR + j * 8 + f];
        }
        #pragma unroll
        for (int i = 0; i < 3; ++i) {
          #pragma unroll
          for (int j = 0; j < 3; ++j) {
            const float sq = xnv[i] + WN[j * 8 + f] - 2.f * dots[i][j];
            D[i][j] = sqrtf(fmaxf(sq, 0.f));
          }
        }

        float cost[4][4];
        cost[0][0] = 0.f; cost[0][1] = BIGV; cost[0][2] = BIGV; cost[0][3] = BIGV;
        unsigned M = 0;
        #pragma unroll
        for (int i = 1; i <= 3; ++i) {
          cost[i][0] = BIGV;
          #pragma unroll
          for (int j = 1; j <= 3; ++j) {
            const float ca = cost[i-1][j-1], cb = cost[i][j-1], cc = cost[i-1][j];
            const int m = (ca <= cb) ? ((ca <= cc) ? 0 : 2) : ((cb <= cc) ? 1 : 2);
            cost[i][j] = D[i-1][j-1] + fminf(fminf(cb, ca), cc);
            M |= (unsigned)m << (2 * (i * 4 + j));
          }
        }

        float acc = dots[2][2];
        int ii = 3, jj = 3;
        bool act = true;
        #pragma unroll
        for (int s = 0; s < 5; ++s) {
          const unsigned st = ((unsigned)(ii & 3) << 2) | (unsigned)(jj & 3);
          const int m  = (M >> (2 * st)) & 3;
          const int i2 = ii - ((m == 1) ? 0 : 1);
          const int j2 = jj - ((m == 2) ? 0 : 1);
          const bool nxt = act && (i2 > 0) && (j2 > 0);
          const int ia = (i2 > 1) ? i2 - 1 : 0;
          const int ja = (j2 > 1) ? j2 - 1 : 0;
          const float v =
              (ia == 0) ? ((ja == 0) ? dots[0][0] : (ja == 1) ? dots[0][1] : dots[0][2])
            : (ia == 1) ? ((ja == 0) ? dots[1][0] : (ja == 1) ? dots[1][1] : dots[1][2])
                        : ((ja == 0) ? dots[2][0] : (ja == 1) ? dots[2][1] : dots[2][2]);
          acc += nxt ? v : 0.f;
          ii = i2; jj = j2; act = nxt;
        }

        if (p < P) out[((size_t)b * P + p) * 8 + f] = fmaxf(acc + BI[f], 0.f);
      }
    }

    __syncthreads();  // G reads done before next rep overwrites Xs
  }
}

extern "C" void kernel_launch(void* const* d_in, const int* in_sizes, int n_in,
                              void* d_out, int out_size, void* d_ws, size_t ws_size,
                              hipStream_t stream) {
  const float* x    = (const float*)d_in[0];
  const float* w    = (const float*)d_in[1];
  const float* bias = (const float*)d_in[2];
  float* out        = (float*)d_out;

  dim3 grid(69, 32);
  dwa_cnn_kernel<<<grid, 128, 0, stream>>>(x, w, bias, out);
}

// Round 8
// 18.806 us; speedup vs baseline: 5.0905x; 5.0905x over previous
//
#include <hip/hip_runtime.h>

// DWA_CNN: B=32, T=2048, C=128, K=3, F=8, P=2046
// v7: (1) forward-accumulated DTW (backtrace eliminated algebraically:
//     pred-argmin in backtrace == forward DP argmin -> A[i][j] = dots + A[pred];
//     identical path selection, only final-sum association differs ~1ulp);
//     (2) (dot,dist) pair table in LDS computed once per (row,q) by the MFMA
//     wave (3x sqrt reuse), aliased onto dead Xs, wave-local rows -> no extra
//     barrier; (3) one-block prep kernel builds pre-swizzled bf16 w-image +
//     WN[24] in d_ws -> main blocks do a linear 4x uint4 copy, waves balanced.

#define TT   30
#define RWS  32
#define DSTR 68     // (dot,dist) table row stride in floats; 8B-aligned, bank-spread
#define BIGV 1234567891011.0f

typedef __attribute__((ext_vector_type(8))) short short8v;
typedef __attribute__((ext_vector_type(4))) float f32x4;

static __device__ inline unsigned pk2(float lo, float hi) {
  unsigned r;
  asm("v_cvt_pk_bf16_f32 %0, %1, %2" : "=v"(r) : "v"(lo), "v"(hi));
  return r;
}
static __device__ inline int swzi(int row, int c) {
  return row * 128 + (((c >> 3) ^ (row & 7)) << 3) + (c & 7);
}

// ---- prep: pre-swizzled bf16 w image (24x128 u16) + WN[24] into ws ----
__global__ __launch_bounds__(128) void prep_kernel(
    const float* __restrict__ w, unsigned short* __restrict__ wimg,
    float* __restrict__ wn)
{
  const int tid = threadIdx.x;
  #pragma unroll
  for (int j = 0; j < 24; ++j) {
    const int i = tid + j * 128;           // i = q*128 + c
    const int q = i >> 7, c = i & 127;
    const int k = q >> 3, f = q & 7;
    const float v = w[(k * 128 + c) * 8 + f];
    wimg[swzi(q, c)] = (unsigned short)(pk2(v, v) & 0xffffu);
  }
  if (tid < 96) {
    const int q = tid >> 2, c0 = (tid & 3) * 32;
    const int k = q >> 3, f = q & 7;
    float s = 0.f;
    #pragma unroll 8
    for (int c = c0; c < c0 + 32; ++c) {
      const float v = w[(k * 128 + c) * 8 + f];
      s = fmaf(v, v, s);
    }
    s += __shfl_xor(s, 1);
    s += __shfl_xor(s, 2);
    if ((tid & 3) == 0) wn[q] = s;
  }
}

// cost/A step for one interior cell; cands order [diag,left,up], first-min wins
static __device__ inline void dpsel(float ca, float cb, float cc,
                                    float Ad, float Al, float Au,
                                    float dist, float dot,
                                    float& costv, float& Av) {
  costv = dist + fminf(fminf(ca, cb), cc);
  const bool d_le_l = (ca <= cb);
  const bool d_le_u = (ca <= cc);
  const bool l_le_u = (cb <= cc);
  Av = dot + (d_le_l ? (d_le_u ? Ad : Au) : (l_le_u ? Al : Au));
}

__global__ __launch_bounds__(128, 4) void dwa_cnn_kernel(
    const float* __restrict__ x, const unsigned short* __restrict__ wimg,
    const float* __restrict__ wnws, const float* __restrict__ bias,
    float* __restrict__ out)
{
  constexpr int T = 2048, C = 128, P = 2046;

  __shared__ alignas(16) float DsG[RWS * DSTR];        // 8.7 KB; first 8 KB = Xs
  __shared__ alignas(16) unsigned short Wb[RWS * 128]; // 8 KB (rows 24..31 zero)
  __shared__ float XN[RWS];
  __shared__ float WN[24];
  __shared__ float BI[8];
  unsigned short* Xs = reinterpret_cast<unsigned short*>(DsG);

  const int tid  = threadIdx.x;
  const int b    = blockIdx.y;
  const int p0   = blockIdx.x * TT;
  const int wave = tid >> 6;
  const int lane = tid & 63;

  // ---- w image -> Wb (linear, pre-swizzled) + zero rows 24..31 ----
  {
    const uint4* src = (const uint4*)wimg;   // 3072 u16 = 384 uint4
    uint4* dst = (uint4*)Wb;
    #pragma unroll
    for (int j = 0; j < 3; ++j) dst[tid + j * 128] = src[tid + j * 128];
    const uint4 z = {0u, 0u, 0u, 0u};
    dst[384 + tid] = z;                      // rows 24..31
  }
  if (tid < 24) WN[tid] = wnws[tid];
  if (tid < 8)  BI[tid] = bias[tid];

  // ---- x -> Xs (bf16 swizzled) + fp32 row norms ----
  {
    const int srow = tid >> 2, c0 = (tid & 3) * 32;
    const int grow = (p0 + srow < T) ? (p0 + srow) : (T - 1);
    const float* xr = &x[((size_t)b * T + grow) * C + c0];
    float4 xv[8];
    #pragma unroll
    for (int m = 0; m < 8; ++m) xv[m] = *(const float4*)(xr + m * 4);
    float xn = 0.f;
    #pragma unroll
    for (int m = 0; m < 8; ++m)
      xn = fmaf(xv[m].x, xv[m].x, fmaf(xv[m].y, xv[m].y,
           fmaf(xv[m].z, xv[m].z, fmaf(xv[m].w, xv[m].w, xn))));
    #pragma unroll
    for (int m = 0; m < 4; ++m) {
      uint4 pkv;
      pkv.x = pk2(xv[2*m].x,   xv[2*m].y);
      pkv.y = pk2(xv[2*m].z,   xv[2*m].w);
      pkv.z = pk2(xv[2*m+1].x, xv[2*m+1].y);
      pkv.w = pk2(xv[2*m+1].z, xv[2*m+1].w);
      *(uint4*)&Xs[swzi(srow, c0 + m * 8)] = pkv;
    }
    xn += __shfl_xor(xn, 1);
    xn += __shfl_xor(xn, 2);
    if ((tid & 3) == 0) XN[srow] = xn;
  }

  __syncthreads();   // Xs, Wb, XN, WN, BI ready

  // ---- fragments (wave-local rows) + MFMA ----
  const int g = lane >> 4;
  const int arow = wave * 16 + (lane & 15);
  const int q0 = lane & 15;
  short8v af[4], b0f[4], b1f[4];
  #pragma unroll
  for (int kk = 0; kk < 4; ++kk) {
    const int oct = kk * 4 + g;
    af[kk]  = *(const short8v*)&Xs[swzi(arow,    oct * 8)];
    b0f[kk] = *(const short8v*)&Wb[swzi(q0,      oct * 8)];
    b1f[kk] = *(const short8v*)&Wb[swzi(q0 + 16, oct * 8)];
  }
  f32x4 acc0 = {0.f, 0.f, 0.f, 0.f}, acc1 = {0.f, 0.f, 0.f, 0.f};
  #pragma unroll
  for (int kk = 0; kk < 4; ++kk) {
    acc0 = __builtin_amdgcn_mfma_f32_16x16x32_bf16(af[kk], b0f[kk], acc0, 0, 0, 0);
    acc1 = __builtin_amdgcn_mfma_f32_16x16x32_bf16(af[kk], b1f[kk], acc1, 0, 0, 0);
  }

  // ---- (dot,dist) table: lane's own 4 rows (C/D layout m89), wave-local ----
  // Xs is dead for this wave's rows (frags in regs; LDS ops in-order per wave),
  // so DsG rows w*16.. overwrite only data this wave staged/read itself.
  {
    const int rq = wave * 16 + (lane >> 4) * 4;
    const float wn0 = WN[q0];
    const float wn1 = (q0 < 8) ? WN[16 + q0] : 0.f;
    #pragma unroll
    for (int r = 0; r < 4; ++r) {
      const int row = rq + r;
      const float xnv = XN[row];
      const float d0 = acc0[r];
      float2 pr0;
      pr0.x = d0;
      pr0.y = sqrtf(fmaxf(xnv + wn0 - 2.f * d0, 0.f));
      *(float2*)&DsG[row * DSTR + q0 * 2] = pr0;
      if (q0 < 8) {
        const float d1 = acc1[r];
        float2 pr1;
        pr1.x = d1;
        pr1.y = sqrtf(fmaxf(xnv + wn1 - 2.f * d1, 0.f));
        *(float2*)&DsG[row * DSTR + (16 + q0) * 2] = pr1;
      }
    }
  }
  __syncthreads();

  // ---- phase 2: forward-accumulated DTW per (p, f) ----
  #pragma unroll
  for (int it = 0; it < 2; ++it) {
    const int o = tid + it * 128;
    if (o < TT * 8) {
      const int pl = o >> 3, f = o & 7;
      const int p  = p0 + pl;

      float dd[3][3], dist[3][3];
      #pragma unroll
      for (int i = 0; i < 3; ++i) {
        #pragma unroll
        for (int k = 0; k < 3; ++k) {
          const float2 pr = *(const float2*)&DsG[(pl + i) * DSTR + (k * 8 + f) * 2];
          dd[i][k] = pr.x;
          dist[i][k] = pr.y;
        }
      }

      // boundary cells: row 1 always steps left, col 1 always steps up
      const float c11 = dist[0][0];
      const float c12 = c11 + dist[0][1];
      const float c13 = c12 + dist[0][2];
      const float c21 = c11 + dist[1][0];
      const float c31 = c21 + dist[2][0];
      const float A11 = dd[0][0];
      const float A12 = A11 + dd[0][1];
      const float A13 = A12 + dd[0][2];
      const float A21 = A11 + dd[1][0];
      const float A31 = A21 + dd[2][0];

      // interior cells (2,2),(2,3),(3,2),(3,3); cands = [diag,left,up]
      float c22, A22, c23, A23, c32, A32, cxx, A33;
      dpsel(c11, c21, c12, A11, A21, A12, dist[1][1], dd[1][1], c22, A22);
      dpsel(c12, c22, c13, A12, A22, A13, dist[1][2], dd[1][2], c23, A23);
      dpsel(c21, c31, c22, A21, A31, A22, dist[2][1], dd[2][1], c32, A32);
      dpsel(c22, c32, c23, A22, A32, A23, dist[2][2], dd[2][2], cxx, A33);

      if (p < P) out[((size_t)b * P + p) * 8 + f] = fmaxf(A33 + BI[f], 0.f);
    }
  }
}

extern "C" void kernel_launch(void* const* d_in, const int* in_sizes, int n_in,
                              void* d_out, int out_size, void* d_ws, size_t ws_size,
                              hipStream_t stream) {
  const float* x    = (const float*)d_in[0];
  const float* w    = (const float*)d_in[1];
  const float* bias = (const float*)d_in[2];
  float* out        = (float*)d_out;

  unsigned short* wimg = (unsigned short*)d_ws;                 // 3072 u16
  float* wn            = (float*)((char*)d_ws + 6144);          // 24 f

  prep_kernel<<<dim3(1), 128, 0, stream>>>(w, wimg, wn);
  dim3 grid(69, 32);   // ceil(2046/30) x B
  dwa_cnn_kernel<<<grid, 128, 0, stream>>>(x, wimg, wn, bias, out);
}

// Round 9
// 14.051 us; speedup vs baseline: 6.8133x; 1.3384x over previous
//
#include <hip/hip_runtime.h>

// DWA_CNN: B=32, T=2048, C=128, K=3, F=8, P=2046
// v8: x loaded global->VGPR directly (no LDS round trip); raw s_barrier with
//     lgkmcnt-only drain so x loads stay in flight across barrier 1; single
//     launch; 4 balanced waves (per-wave in-register WN/XN via shfl);
//     (dot,dist) LDS table + forward-accumulated DTW (validated in v7).

#define TT   62
#define RWS  64
#define DSTR 68

typedef __attribute__((ext_vector_type(8))) short short8v;
typedef __attribute__((ext_vector_type(4))) float f32x4;

static __device__ inline unsigned pk2(float lo, float hi) {
  unsigned r;
  asm("v_cvt_pk_bf16_f32 %0, %1, %2" : "=v"(r) : "v"(lo), "v"(hi));
  return r;
}
static __device__ inline float bf2f(unsigned short h) {
  return __uint_as_float(((unsigned)h) << 16);
}
static __device__ inline int swzi(int row, int c) {
  return row * 128 + (((c >> 3) ^ (row & 7)) << 3) + (c & 7);
}

// interior DTW cell; cands order [diag,left,up], first-min tie-break (jnp.argmin)
static __device__ inline void dpsel(float ca, float cb, float cc,
                                    float Ad, float Al, float Au,
                                    float dist, float dot,
                                    float& costv, float& Av) {
  costv = dist + fminf(fminf(ca, cb), cc);
  const bool d_le_l = (ca <= cb);
  const bool d_le_u = (ca <= cc);
  const bool l_le_u = (cb <= cc);
  Av = dot + (d_le_l ? (d_le_u ? Ad : Au) : (l_le_u ? Al : Au));
}

__global__ __launch_bounds__(256, 5) void dwa_cnn_kernel(
    const float* __restrict__ x, const float* __restrict__ w,
    const float* __restrict__ bias, float* __restrict__ out)
{
  constexpr int T = 2048, C = 128, P = 2046;

  __shared__ alignas(16) unsigned short Wb[32 * 128];  // 8 KB (rows 24..31 zero)
  __shared__ alignas(16) float DsG[RWS * DSTR];        // 17.4 KB (dot,dist) pairs
  __shared__ float BI[8];

  const int tid  = threadIdx.x;
  const int b    = blockIdx.y;
  const int p0   = blockIdx.x * TT;      // 33*62 = 2046 exact; rows p0..p0+63 <= 2047
  const int wave = tid >> 6;
  const int lane = tid & 63;
  const int g    = lane >> 4, l15 = lane & 15;
  const int arow = wave * 16 + l15;      // this lane's A-row within block tile

  // ---- issue x loads FIRST (8 dwordx4, 32B/lane/k-step, stay in flight) ----
  const float* xr = &x[((size_t)b * T + p0 + arow) * C + g * 8];
  float4 xa[8];
  #pragma unroll
  for (int kk = 0; kk < 4; ++kk) {
    xa[2 * kk]     = *(const float4*)(xr + kk * 32);
    xa[2 * kk + 1] = *(const float4*)(xr + kk * 32 + 4);
  }

  // ---- w -> Wb (bf16, swizzled); 3 coalesced float4 + 12 b16 stores ----
  #pragma unroll
  for (int j = 0; j < 3; ++j) {
    const int i4 = j * 1024 + tid * 4;     // i = k*1024 + c*8 + f
    const float4 wv = *(const float4*)&w[i4];
    const int k = i4 >> 10, c = (i4 >> 3) & 127, f0 = i4 & 7;
    const int q = k * 8 + f0;
    Wb[swzi(q + 0, c)] = (unsigned short)(pk2(wv.x, wv.x) & 0xffffu);
    Wb[swzi(q + 1, c)] = (unsigned short)(pk2(wv.y, wv.y) & 0xffffu);
    Wb[swzi(q + 2, c)] = (unsigned short)(pk2(wv.z, wv.z) & 0xffffu);
    Wb[swzi(q + 3, c)] = (unsigned short)(pk2(wv.w, wv.w) & 0xffffu);
  }
  { uint2 z = {0u, 0u}; *(uint2*)&Wb[3072 + tid * 4] = z; }  // rows 24..31 = 0
  if (tid < 8) BI[tid] = bias[tid];

  // barrier 1: publish Wb/BI (LDS only) -- do NOT drain vmcnt (x in flight)
  asm volatile("s_waitcnt lgkmcnt(0)\n\ts_barrier" ::: "memory");

  // ---- x cvt -> A-frags + fp32 row norm (vmcnt waits inserted on use) ----
  short8v af[4];
  float xn = 0.f;
  #pragma unroll
  for (int kk = 0; kk < 4; ++kk) {
    const float4 a = xa[2 * kk], c4 = xa[2 * kk + 1];
    xn = fmaf(a.x, a.x, fmaf(a.y, a.y, fmaf(a.z, a.z, fmaf(a.w, a.w, xn))));
    xn = fmaf(c4.x, c4.x, fmaf(c4.y, c4.y, fmaf(c4.z, c4.z, fmaf(c4.w, c4.w, xn))));
    uint4 pr;
    pr.x = pk2(a.x, a.y);  pr.y = pk2(a.z, a.w);
    pr.z = pk2(c4.x, c4.y); pr.w = pk2(c4.z, c4.w);
    af[kk] = *(short8v*)&pr;
  }
  xn += __shfl_xor(xn, 16);   // combine the 4 g-chunks of this row
  xn += __shfl_xor(xn, 32);   // -> full |x_row|^2 in all 4 copies

  // ---- B-frags + MFMA ----
  const int q0 = l15;
  short8v b0f[4], b1f[4];
  #pragma unroll
  for (int kk = 0; kk < 4; ++kk) {
    const int oct = kk * 4 + g;
    b0f[kk] = *(const short8v*)&Wb[swzi(q0,      oct * 8)];
    b1f[kk] = *(const short8v*)&Wb[swzi(q0 + 16, oct * 8)];
  }
  f32x4 acc0 = {0.f, 0.f, 0.f, 0.f}, acc1 = {0.f, 0.f, 0.f, 0.f};
  #pragma unroll
  for (int kk = 0; kk < 4; ++kk) {
    acc0 = __builtin_amdgcn_mfma_f32_16x16x32_bf16(af[kk], b0f[kk], acc0, 0, 0, 0);
    acc1 = __builtin_amdgcn_mfma_f32_16x16x32_bf16(af[kk], b1f[kk], acc1, 0, 0, 0);
  }

  // ---- per-wave WN from own B-frags (balanced, no LDS) ----
  float wn0 = 0.f, wn1 = 0.f;
  #pragma unroll
  for (int kk = 0; kk < 4; ++kk) {
    #pragma unroll
    for (int e = 0; e < 8; ++e) {
      const float v0 = bf2f((unsigned short)b0f[kk][e]); wn0 = fmaf(v0, v0, wn0);
      const float v1 = bf2f((unsigned short)b1f[kk][e]); wn1 = fmaf(v1, v1, wn1);
    }
  }
  wn0 += __shfl_xor(wn0, 16); wn0 += __shfl_xor(wn0, 32);
  wn1 += __shfl_xor(wn1, 16); wn1 += __shfl_xor(wn1, 32);

  // ---- (dot,dist) table; C/D layout: col=lane&15, row=g*4+r [m89] ----
  {
    const int rq = g * 4;
    #pragma unroll
    for (int r = 0; r < 4; ++r) {
      const float xnv = __shfl(xn, rq + r);        // norm of row wave*16+rq+r
      const int row = wave * 16 + rq + r;
      const float d0 = acc0[r];
      float2 pv0;
      pv0.x = d0;
      pv0.y = sqrtf(fmaxf(xnv + wn0 - 2.f * d0, 0.f));
      *(float2*)&DsG[row * DSTR + q0 * 2] = pv0;
      if (q0 < 8) {
        const float d1 = acc1[r];
        float2 pv1;
        pv1.x = d1;
        pv1.y = sqrtf(fmaxf(xnv + wn1 - 2.f * d1, 0.f));
        *(float2*)&DsG[row * DSTR + (16 + q0) * 2] = pv1;
      }
    }
  }

  // barrier 2: publish DsG (LDS only)
  asm volatile("s_waitcnt lgkmcnt(0)\n\ts_barrier" ::: "memory");

  // ---- phase 2: forward-accumulated DTW per (p, f) ----
  #pragma unroll
  for (int it = 0; it < 2; ++it) {
    const int o = tid + it * 256;
    if (o < TT * 8) {
      const int pl = o >> 3, f = o & 7;

      float dd[3][3], dist[3][3];
      #pragma unroll
      for (int i = 0; i < 3; ++i) {
        #pragma unroll
        for (int k = 0; k < 3; ++k) {
          const float2 pr = *(const float2*)&DsG[(pl + i) * DSTR + (k * 8 + f) * 2];
          dd[i][k] = pr.x;
          dist[i][k] = pr.y;
        }
      }

      // boundary cells: row 1 always steps left, col 1 always steps up
      const float c11 = dist[0][0];
      const float c12 = c11 + dist[0][1];
      const float c13 = c12 + dist[0][2];
      const float c21 = c11 + dist[1][0];
      const float c31 = c21 + dist[2][0];
      const float A11 = dd[0][0];
      const float A12 = A11 + dd[0][1];
      const float A13 = A12 + dd[0][2];
      const float A21 = A11 + dd[1][0];
      const float A31 = A21 + dd[2][0];

      float c22, A22, c23, A23, c32, A32, cxx, A33;
      dpsel(c11, c21, c12, A11, A21, A12, dist[1][1], dd[1][1], c22, A22);
      dpsel(c12, c22, c13, A12, A22, A13, dist[1][2], dd[1][2], c23, A23);
      dpsel(c21, c31, c22, A21, A31, A22, dist[2][1], dd[2][1], c32, A32);
      dpsel(c22, c32, c23, A22, A32, A23, dist[2][2], dd[2][2], cxx, A33);

      out[((size_t)b * P + p0 + pl) * 8 + f] = fmaxf(A33 + BI[f], 0.f);
    }
  }
}

extern "C" void kernel_launch(void* const* d_in, const int* in_sizes, int n_in,
                              void* d_out, int out_size, void* d_ws, size_t ws_size,
                              hipStream_t stream) {
  const float* x    = (const float*)d_in[0];
  const float* w    = (const float*)d_in[1];
  const float* bias = (const float*)d_in[2];
  float* out        = (float*)d_out;

  dim3 grid(33, 32);   // 33*62 = 2046 positions
  dwa_cnn_kernel<<<grid, 256, 0, stream>>>(x, w, bias, out);
}

// Round 10
// 13.591 us; speedup vs baseline: 7.0436x; 1.0338x over previous
//
#include <hip/hip_runtime.h>

// DWA_CNN: B=32, T=2048, C=128, K=3, F=8, P=2046
// v9: v8 + (1) w-loads issued BEFORE x-loads (vmcnt retires in-order: staging
//     no longer serializes behind cold x arrival); (2) phase-2 f-pairing:
//     9x ds_read_b128 serves two outputs (f, f+1) + float2 stores; (3) WN via
//     self-MFMA diagonal (8 MFMA + shfl replace ~128 VALU/wave); (4)
//     launch_bounds(256,4) -> 128 VGPR cap, no spill risk.

#define TT   62
#define RWS  64
#define DSTR 68   // floats; 272 B = 17*16 -> b128-aligned rows

typedef __attribute__((ext_vector_type(8))) short short8v;
typedef __attribute__((ext_vector_type(4))) float f32x4;

static __device__ inline unsigned pk2(float lo, float hi) {
  unsigned r;
  asm("v_cvt_pk_bf16_f32 %0, %1, %2" : "=v"(r) : "v"(lo), "v"(hi));
  return r;
}
static __device__ inline int swzi(int row, int c) {
  return row * 128 + (((c >> 3) ^ (row & 7)) << 3) + (c & 7);
}

// interior DTW cell; cands order [diag,left,up], first-min tie-break (jnp.argmin)
static __device__ inline void dpsel(float ca, float cb, float cc,
                                    float Ad, float Al, float Au,
                                    float dist, float dot,
                                    float& costv, float& Av) {
  costv = dist + fminf(fminf(ca, cb), cc);
  const bool d_le_l = (ca <= cb);
  const bool d_le_u = (ca <= cc);
  const bool l_le_u = (cb <= cc);
  Av = dot + (d_le_l ? (d_le_u ? Ad : Au) : (l_le_u ? Al : Au));
}

__global__ __launch_bounds__(256, 4) void dwa_cnn_kernel(
    const float* __restrict__ x, const float* __restrict__ w,
    const float* __restrict__ bias, float* __restrict__ out)
{
  constexpr int T = 2048, C = 128, P = 2046;

  __shared__ alignas(16) unsigned short Wb[32 * 128];  // 8 KB (rows 24..31 zero)
  __shared__ alignas(16) float DsG[RWS * DSTR];        // 17.4 KB (dot,dist) pairs
  __shared__ float BI[8];

  const int tid  = threadIdx.x;
  const int b    = blockIdx.y;
  const int p0   = blockIdx.x * TT;      // 33*62 = 2046 exact; rows <= 2047
  const int wave = tid >> 6;
  const int lane = tid & 63;
  const int g    = lane >> 4, l15 = lane & 15;
  const int arow = wave * 16 + l15;

  // ---- issue w loads FIRST (oldest in queue -> staging never waits on x) ----
  float4 wv[3];
  #pragma unroll
  for (int j = 0; j < 3; ++j)
    wv[j] = *(const float4*)&w[j * 1024 + tid * 4];
  const float breg = (tid < 8) ? bias[tid] : 0.f;

  // ---- issue x loads (8 dwordx4 = 2 contiguous per k-step; in flight) ----
  const float* xr = &x[((size_t)b * T + p0 + arow) * C + g * 8];
  float4 xa[8];
  #pragma unroll
  for (int kk = 0; kk < 4; ++kk) {
    xa[2 * kk]     = *(const float4*)(xr + kk * 32);
    xa[2 * kk + 1] = *(const float4*)(xr + kk * 32 + 4);
  }

  // ---- stage w -> Wb (bf16, swizzled) ----
  #pragma unroll
  for (int j = 0; j < 3; ++j) {
    const int i4 = j * 1024 + tid * 4;     // i = k*1024 + c*8 + f
    const int k = i4 >> 10, c = (i4 >> 3) & 127, f0 = i4 & 7;
    const int q = k * 8 + f0;
    Wb[swzi(q + 0, c)] = (unsigned short)pk2(wv[j].x, wv[j].x);
    Wb[swzi(q + 1, c)] = (unsigned short)pk2(wv[j].y, wv[j].y);
    Wb[swzi(q + 2, c)] = (unsigned short)pk2(wv[j].z, wv[j].z);
    Wb[swzi(q + 3, c)] = (unsigned short)pk2(wv[j].w, wv[j].w);
  }
  { uint2 z = {0u, 0u}; *(uint2*)&Wb[3072 + tid * 4] = z; }  // rows 24..31 = 0
  if (tid < 8) BI[tid] = breg;

  // barrier 1: publish Wb/BI (LDS only) -- x loads stay in flight
  asm volatile("s_waitcnt lgkmcnt(0)\n\ts_barrier" ::: "memory");

  // ---- x cvt -> A-frags + fp32 row norm ----
  short8v af[4];
  float xn = 0.f;
  #pragma unroll
  for (int kk = 0; kk < 4; ++kk) {
    const float4 a = xa[2 * kk], c4 = xa[2 * kk + 1];
    xn = fmaf(a.x, a.x, fmaf(a.y, a.y, fmaf(a.z, a.z, fmaf(a.w, a.w, xn))));
    xn = fmaf(c4.x, c4.x, fmaf(c4.y, c4.y, fmaf(c4.z, c4.z, fmaf(c4.w, c4.w, xn))));
    uint4 pr;
    pr.x = pk2(a.x, a.y);   pr.y = pk2(a.z, a.w);
    pr.z = pk2(c4.x, c4.y); pr.w = pk2(c4.z, c4.w);
    af[kk] = *(short8v*)&pr;
  }
  xn += __shfl_xor(xn, 16);
  xn += __shfl_xor(xn, 32);   // all 4 copies of row-norm

  // ---- B-frags ----
  const int q0 = l15;
  short8v b0f[4], b1f[4];
  #pragma unroll
  for (int kk = 0; kk < 4; ++kk) {
    const int oct = kk * 4 + g;
    b0f[kk] = *(const short8v*)&Wb[swzi(q0,      oct * 8)];
    b1f[kk] = *(const short8v*)&Wb[swzi(q0 + 16, oct * 8)];
  }

  // ---- MFMA: G tiles + WN diagonals ----
  f32x4 acc0 = {0.f, 0.f, 0.f, 0.f}, acc1 = {0.f, 0.f, 0.f, 0.f};
  f32x4 aw0  = {0.f, 0.f, 0.f, 0.f}, aw1  = {0.f, 0.f, 0.f, 0.f};
  #pragma unroll
  for (int kk = 0; kk < 4; ++kk) {
    acc0 = __builtin_amdgcn_mfma_f32_16x16x32_bf16(af[kk], b0f[kk], acc0, 0, 0, 0);
    acc1 = __builtin_amdgcn_mfma_f32_16x16x32_bf16(af[kk], b1f[kk], acc1, 0, 0, 0);
    aw0  = __builtin_amdgcn_mfma_f32_16x16x32_bf16(b0f[kk], b0f[kk], aw0, 0, 0, 0);
    aw1  = __builtin_amdgcn_mfma_f32_16x16x32_bf16(b1f[kk], b1f[kk], aw1, 0, 0, 0);
  }

  // ---- WN[q] = diag of aw: value at lane ((q>>2)<<4)|q, reg q&3 ----
  float wn0, wn1;
  {
    const int src = ((l15 >> 2) << 4) | l15;
    const int rsel = l15 & 3;
    float s0 = __shfl(aw0[0], src), s1 = __shfl(aw0[1], src);
    float s2 = __shfl(aw0[2], src), s3 = __shfl(aw0[3], src);
    wn0 = (rsel == 0) ? s0 : (rsel == 1) ? s1 : (rsel == 2) ? s2 : s3;
    s0 = __shfl(aw1[0], src); s1 = __shfl(aw1[1], src);
    s2 = __shfl(aw1[2], src); s3 = __shfl(aw1[3], src);
    wn1 = (rsel == 0) ? s0 : (rsel == 1) ? s1 : (rsel == 2) ? s2 : s3;
  }

  // ---- (dot,dist) table; C/D layout: col=lane&15, row=g*4+r [m89] ----
  {
    const int rq = g * 4;
    #pragma unroll
    for (int r = 0; r < 4; ++r) {
      const float xnv = __shfl(xn, rq + r);     // norm of row wave*16+rq+r
      const int row = wave * 16 + rq + r;
      const float d0 = acc0[r];
      float2 pv0;
      pv0.x = d0;
      pv0.y = sqrtf(fmaxf(xnv + wn0 - 2.f * d0, 0.f));
      *(float2*)&DsG[row * DSTR + q0 * 2] = pv0;
      if (q0 < 8) {
        const float d1 = acc1[r];
        float2 pv1;
        pv1.x = d1;
        pv1.y = sqrtf(fmaxf(xnv + wn1 - 2.f * d1, 0.f));
        *(float2*)&DsG[row * DSTR + (16 + q0) * 2] = pv1;
      }
    }
  }

  // barrier 2: publish DsG (LDS only)
  asm volatile("s_waitcnt lgkmcnt(0)\n\ts_barrier" ::: "memory");

  // ---- phase 2: thread = (pl, f-pair); 9x b128 reads serve 2 outputs ----
  if (tid < TT * 4) {
    const int pl = tid >> 2, f0 = (tid & 3) * 2;

    float d0[3][3], s0[3][3], d1[3][3], s1[3][3];
    #pragma unroll
    for (int i = 0; i < 3; ++i) {
      #pragma unroll
      for (int k = 0; k < 3; ++k) {
        const float4 pr = *(const float4*)&DsG[(pl + i) * DSTR + (k * 8 + f0) * 2];
        d0[i][k] = pr.x; s0[i][k] = pr.y;   // f0
        d1[i][k] = pr.z; s1[i][k] = pr.w;   // f0+1
      }
    }

    float2 o;
    {
      const float c11 = s0[0][0];
      const float c12 = c11 + s0[0][1];
      const float c13 = c12 + s0[0][2];
      const float c21 = c11 + s0[1][0];
      const float c31 = c21 + s0[2][0];
      const float A11 = d0[0][0];
      const float A12 = A11 + d0[0][1];
      const float A13 = A12 + d0[0][2];
      const float A21 = A11 + d0[1][0];
      const float A31 = A21 + d0[2][0];
      float c22, A22, c23, A23, c32, A32, cxx, A33;
      dpsel(c11, c21, c12, A11, A21, A12, s0[1][1], d0[1][1], c22, A22);
      dpsel(c12, c22, c13, A12, A22, A13, s0[1][2], d0[1][2], c23, A23);
      dpsel(c21, c31, c22, A21, A31, A22, s0[2][1], d0[2][1], c32, A32);
      dpsel(c22, c32, c23, A22, A32, A23, s0[2][2], d0[2][2], cxx, A33);
      o.x = fmaxf(A33 + BI[f0], 0.f);
    }
    {
      const float c11 = s1[0][0];
      const float c12 = c11 + s1[0][1];
      const float c13 = c12 + s1[0][2];
      const float c21 = c11 + s1[1][0];
      const float c31 = c21 + s1[2][0];
      const float A11 = d1[0][0];
      const float A12 = A11 + d1[0][1];
      const float A13 = A12 + d1[0][2];
      const float A21 = A11 + d1[1][0];
      const float A31 = A21 + d1[2][0];
      float c22, A22, c23, A23, c32, A32, cxx, A33;
      dpsel(c11, c21, c12, A11, A21, A12, s1[1][1], d1[1][1], c22, A22);
      dpsel(c12, c22, c13, A12, A22, A13, s1[1][2], d1[1][2], c23, A23);
      dpsel(c21, c31, c22, A21, A31, A22, s1[2][1], d1[2][1], c32, A32);
      dpsel(c22, c32, c23, A22, A32, A23, s1[2][2], d1[2][2], cxx, A33);
      o.y = fmaxf(A33 + BI[f0 + 1], 0.f);
    }

    *(float2*)&out[((size_t)b * P + p0 + pl) * 8 + f0] = o;
  }
}

extern "C" void kernel_launch(void* const* d_in, const int* in_sizes, int n_in,
                              void* d_out, int out_size, void* d_ws, size_t ws_size,
                              hipStream_t stream) {
  const float* x    = (const float*)d_in[0];
  const float* w    = (const float*)d_in[1];
  const float* bias = (const float*)d_in[2];
  float* out        = (float*)d_out;

  dim3 grid(33, 32);   // 33*62 = 2046 positions
  dwa_cnn_kernel<<<grid, 256, 0, stream>>>(x, w, bias, out);
}